// Round 3
// baseline (508.645 us; speedup 1.0000x reference)
//
#include <hip/hip_runtime.h>
#include <stdint.h>

#define NTOK 16384
#define DIM 2048
#define HIDDEN 1408
#define NEXP 8
#define NPRIME 2816   // 2*HIDDEN, 16-col interleaved w1/w3

typedef short short8 __attribute__((ext_vector_type(8)));
typedef float f32x4 __attribute__((ext_vector_type(4)));
typedef unsigned short u16;

// round-to-nearest-even fp32 -> bf16
__device__ __forceinline__ u16 f2bf(float f) {
    uint32_t u = __float_as_uint(f);
    return (u16)((u + 0x7fffu + ((u >> 16) & 1u)) >> 16);
}

// async global->LDS, 16B per lane (LDS dest = wave-uniform base + lane*16)
__device__ __forceinline__ void gload16(const u16* g, u16* l) {
    __builtin_amdgcn_global_load_lds(
        (const __attribute__((address_space(1))) void*)g,
        (__attribute__((address_space(3))) void*)l,
        16, 0, 0);
}

// stage a 256x64 A half (2048 chunks of 16B, 4 per thread), pre-swizzled source
__device__ __forceinline__ void stageA(const u16* Ag, size_t lda, int k2, u16* dst, int tid) {
    #pragma unroll
    for (int it = 0; it < 4; ++it) {
        int c   = it * 512 + tid;            // 0..2047
        int row = c >> 3;                    // 0..255
        int sc  = ((c & 7) ^ (row & 7)) << 3;
        gload16(Ag + (size_t)row * lda + k2 + sc, dst + c * 16 / 2);
    }
}
// stage a 128x64 B tile (1024 chunks, 2 per thread)
__device__ __forceinline__ void stageB(const u16* Bg, size_t ldb, int k2, u16* dst, int tid) {
    #pragma unroll
    for (int it = 0; it < 2; ++it) {
        int c   = it * 512 + tid;            // 0..1023
        int row = c >> 3;                    // 0..127
        int sc  = ((c & 7) ^ (row & 7)) << 3;
        gload16(Bg + (size_t)row * ldb + k2 + sc, dst + c * 8);
    }
}

// ---------------------------------------------------------------- cvt f32->bf16
__global__ __launch_bounds__(256) void cvt_kernel(const float* __restrict__ src,
                                                  u16* __restrict__ dst, long n) {
    long i0 = ((long)blockIdx.x * 256 + threadIdx.x) * 8;
    long stride = (long)gridDim.x * 256 * 8;
    for (long i = i0; i < n; i += stride) {
        float4 a = *(const float4*)(src + i);
        float4 b = *(const float4*)(src + i + 4);
        uint4 o;
        o.x = (uint32_t)f2bf(a.x) | ((uint32_t)f2bf(a.y) << 16);
        o.y = (uint32_t)f2bf(a.z) | ((uint32_t)f2bf(a.w) << 16);
        o.z = (uint32_t)f2bf(b.x) | ((uint32_t)f2bf(b.y) << 16);
        o.w = (uint32_t)f2bf(b.z) | ((uint32_t)f2bf(b.w) << 16);
        *(uint4*)(dst + i) = o;
    }
}

// ---------------------------------------------------------------- cvt+interleave w1/w3
__global__ __launch_bounds__(256) void cvt13_kernel(const float* __restrict__ w1,
                                                    const float* __restrict__ w3,
                                                    u16* __restrict__ dst) {
    const int r  = blockIdx.x;            // 0 .. 8*2816-1
    const int e  = r / NPRIME;
    const int np = r - e * NPRIME;
    const int p  = np >> 5;
    const int s  = (np >> 4) & 1;
    const int c  = np & 15;
    const int hcol = p * 16 + c;
    const float* src = (s ? w3 : w1) + ((size_t)e * HIDDEN + hcol) * DIM;
    u16* d = dst + (size_t)r * DIM;
    const int i = threadIdx.x * 8;
    float4 a = *(const float4*)(src + i);
    float4 b = *(const float4*)(src + i + 4);
    uint4 o;
    o.x = (uint32_t)f2bf(a.x) | ((uint32_t)f2bf(a.y) << 16);
    o.y = (uint32_t)f2bf(a.z) | ((uint32_t)f2bf(a.w) << 16);
    o.z = (uint32_t)f2bf(b.x) | ((uint32_t)f2bf(b.y) << 16);
    o.w = (uint32_t)f2bf(b.z) | ((uint32_t)f2bf(b.w) << 16);
    *(uint4*)(d + i) = o;
}

// ======================= deep-pipelined GEMM cores =======================
// BM=256, BN=128, BK=64, 512 thr = 8 waves (4M x 2N), wave tile 64x64.
// 3-slot LDS ring; tile t+2 staged into slot (t+2)%3 during tile t (its
// previous contents were fully read by end of tile t-1 -> race-free by
// construction, independent of load landing time). Boundary sync only:
// s_waitcnt vmcnt(6) (= tile t+2's 6 per-thread loads still in flight,
// tile t+1 proven landed) + raw s_barrier. Never vmcnt(0) in steady state.

#define GEMM_CORE(LD, NT, ACC_DECL)                                              \
    const int tid  = threadIdx.x;                                                \
    const int lane = tid & 63;                                                   \
    const int wid  = tid >> 6;                                                   \
    const int wr   = wid >> 1;     /* 0..3 -> 64-row group */                    \
    const int wc   = wid & 1;      /* 0..1 -> 64-col group */                    \
    const int lq   = lane >> 4;                                                  \
    const int lm   = lane & 15;                                                  \
    ACC_DECL;                                                                    \
    stageA(Ag, LD, 0,  As[0], tid);  stageB(Bg, LD, 0,  Bs[0], tid);             \
    stageA(Ag, LD, 64, As[1], tid);  stageB(Bg, LD, 64, Bs[1], tid);             \
    asm volatile("s_waitcnt vmcnt(6)" ::: "memory");                             \
    __builtin_amdgcn_s_barrier();                                                \
    for (int t = 0; t < NT; ++t) {                                               \
        const int p = t % 3, q = (t + 2) % 3;                                    \
        const u16* Asp = As[p];                                                  \
        const u16* Bsp = Bs[p];                                                  \
        short8 af0[2][2], af1[2][2], bf[4][2];                                   \
        _Pragma("unroll")                                                        \
        for (int i = 0; i < 2; ++i)                                              \
            _Pragma("unroll")                                                    \
            for (int kk = 0; kk < 2; ++kk) {                                     \
                int ar = wr * 64 + i * 16 + lm;                                  \
                int gc = kk * 4 + lq;                                            \
                af0[i][kk] = *(const short8*)&Asp[ar * 64 + ((gc ^ (ar & 7)) << 3)]; \
            }                                                                    \
        _Pragma("unroll")                                                        \
        for (int j = 0; j < 4; ++j)                                              \
            _Pragma("unroll")                                                    \
            for (int kk = 0; kk < 2; ++kk) {                                     \
                int br = wc * 64 + j * 16 + lm;                                  \
                int gc = kk * 4 + lq;                                            \
                bf[j][kk] = *(const short8*)&Bsp[br * 64 + ((gc ^ (br & 7)) << 3)]; \
            }                                                                    \
        if (t + 2 < NT) stageA(Ag, LD, (t + 2) * 64, As[q], tid);                \
        __builtin_amdgcn_s_barrier();                                            \
        __builtin_amdgcn_s_setprio(1);                                           \
        _Pragma("unroll")                                                        \
        for (int kk = 0; kk < 2; ++kk)                                           \
            _Pragma("unroll")                                                    \
            for (int i = 0; i < 2; ++i)                                          \
                _Pragma("unroll")                                                \
                for (int j = 0; j < 4; ++j)                                      \
                    acc[i][j] = __builtin_amdgcn_mfma_f32_16x16x32_bf16(         \
                        af0[i][kk], bf[j][kk], acc[i][j], 0, 0, 0);              \
        __builtin_amdgcn_s_setprio(0);                                           \
        __builtin_amdgcn_s_barrier();                                            \
        _Pragma("unroll")                                                        \
        for (int i = 0; i < 2; ++i)                                              \
            _Pragma("unroll")                                                    \
            for (int kk = 0; kk < 2; ++kk) {                                     \
                int ar = wr * 64 + (i + 2) * 16 + lm;                            \
                int gc = kk * 4 + lq;                                            \
                af1[i][kk] = *(const short8*)&Asp[ar * 64 + ((gc ^ (ar & 7)) << 3)]; \
            }                                                                    \
        if (t + 2 < NT) stageB(Bg, LD, (t + 2) * 64, Bs[q], tid);                \
        __builtin_amdgcn_s_barrier();                                            \
        __builtin_amdgcn_s_setprio(1);                                           \
        _Pragma("unroll")                                                        \
        for (int kk = 0; kk < 2; ++kk)                                           \
            _Pragma("unroll")                                                    \
            for (int i = 0; i < 2; ++i)                                          \
                _Pragma("unroll")                                                \
                for (int j = 0; j < 4; ++j)                                      \
                    acc[i + 2][j] = __builtin_amdgcn_mfma_f32_16x16x32_bf16(     \
                        af1[i][kk], bf[j][kk], acc[i + 2][j], 0, 0, 0);          \
        __builtin_amdgcn_s_setprio(0);                                           \
        if (t + 2 < NT) { asm volatile("s_waitcnt vmcnt(6)" ::: "memory"); }     \
        else            { asm volatile("s_waitcnt vmcnt(0)" ::: "memory"); }     \
        __builtin_amdgcn_s_barrier();                                            \
    }

// ---------------------------------------------------------------- FFN1 (X @ B'^T, fused SwiGLU)
__global__ __launch_bounds__(512, 1) void ffn1_kernel(
    const u16* __restrict__ xb, const u16* __restrict__ wb13,
    const int* __restrict__ ntpe, u16* __restrict__ hb)
{
    __shared__ u16 As[3][256 * 64];
    __shared__ u16 Bs[3][128 * 64];

    // XCD-aware swizzle: nwg = 8*22*8 = 1408, %8==0. mt fastest in logical order.
    const int nwg = 8 * 22 * NEXP;
    int logical = (blockIdx.x & 7) * (nwg >> 3) + (blockIdx.x >> 3);
    const int mt = logical & 7;
    int rest = logical >> 3;
    const int nt = rest % 22;
    const int e  = rest / 22;

    int base = 0;
    #pragma unroll
    for (int i = 0; i < NEXP; ++i) base += (i < e) ? ntpe[i] : 0;
    const int cnt = ntpe[e];
    if (mt * 256 >= cnt) return;   // block-uniform

    const size_t m0 = (size_t)base + (size_t)mt * 256;
    const u16* Ag = xb   + m0 * DIM;
    const u16* Bg = wb13 + ((size_t)e * NPRIME + nt * 128) * DIM;

    GEMM_CORE(DIM, 32, f32x4 acc[4][4] = {})

    // epilogue: frag j even = c1, j odd = c3 (same 16 hidden cols)
    #pragma unroll
    for (int i = 0; i < 4; ++i)
        #pragma unroll
        for (int jp = 0; jp < 4; jp += 2) {
            const int p = nt * 4 + wc * 2 + (jp >> 1);
            #pragma unroll
            for (int r = 0; r < 4; ++r) {
                int mrow = mt * 256 + wr * 64 + i * 16 + lq * 4 + r;
                if (mrow < cnt) {
                    float v1 = acc[i][jp][r];
                    float v3 = acc[i][jp + 1][r];
                    float h = (v1 / (1.f + __expf(-v1))) * v3;
                    hb[((size_t)base + mrow) * HIDDEN + p * 16 + lm] = f2bf(h);
                }
            }
        }
}

// ---------------------------------------------------------------- FFN2 (h @ W2^T -> out fp32)
__global__ __launch_bounds__(512, 1) void ffn2_kernel(
    const u16* __restrict__ hb, const u16* __restrict__ w2b,
    const int* __restrict__ ntpe, float* __restrict__ out)
{
    __shared__ u16 As[3][256 * 64];
    __shared__ u16 Bs[3][128 * 64];

    const int nwg = 8 * 16 * NEXP;   // 1024, %8==0
    int logical = (blockIdx.x & 7) * (nwg >> 3) + (blockIdx.x >> 3);
    const int mt = logical & 7;
    int rest = logical >> 3;
    const int nt = rest % 16;
    const int e  = rest / 16;

    int base = 0;
    #pragma unroll
    for (int i = 0; i < NEXP; ++i) base += (i < e) ? ntpe[i] : 0;
    const int cnt = ntpe[e];
    if (mt * 256 >= cnt) return;

    const size_t m0 = (size_t)base + (size_t)mt * 256;
    const u16* Ag = hb  + m0 * HIDDEN;
    const u16* Bg = w2b + ((size_t)e * DIM + nt * 128) * HIDDEN;

    GEMM_CORE(HIDDEN, 22, f32x4 acc[4][4] = {})

    #pragma unroll
    for (int i = 0; i < 4; ++i)
        #pragma unroll
        for (int j = 0; j < 4; ++j)
            #pragma unroll
            for (int r = 0; r < 4; ++r) {
                int mrow = mt * 256 + wr * 64 + i * 16 + lq * 4 + r;
                if (mrow < cnt)
                    out[((size_t)base + mrow) * DIM + (nt * 128 + wc * 64 + j * 16 + lm)] = acc[i][j][r];
            }
}

// ---------------------------------------------------------------- launch
extern "C" void kernel_launch(void* const* d_in, const int* in_sizes, int n_in,
                              void* d_out, int out_size, void* d_ws, size_t ws_size,
                              hipStream_t stream) {
    const float* x  = (const float*)d_in[0];
    const float* w1 = (const float*)d_in[1];
    const float* w2 = (const float*)d_in[2];  // dict order: x, w1, w2, w3, ntpe
    const float* w3 = (const float*)d_in[3];
    const int* ntpe = (const int*)d_in[4];
    float* out = (float*)d_out;

    u16* xb   = (u16*)d_ws;
    u16* wb13 = xb   + (size_t)NTOK * DIM;
    u16* w2b  = wb13 + (size_t)NEXP * NPRIME * DIM;
    u16* hb   = w2b  + (size_t)NEXP * DIM * HIDDEN;

    cvt_kernel<<<2048, 256, 0, stream>>>(x,  xb,  (long)NTOK * DIM);
    cvt_kernel<<<2048, 256, 0, stream>>>(w2, w2b, (long)NEXP * DIM * HIDDEN);
    cvt13_kernel<<<NEXP * NPRIME, 256, 0, stream>>>(w1, w3, wb13);

    ffn1_kernel<<<8 * 22 * NEXP, 512, 0, stream>>>(xb, wb13, ntpe, hb);
    ffn2_kernel<<<8 * 16 * NEXP, 512, 0, stream>>>(hb, w2b, ntpe, out);
}